// Round 8
// baseline (568.158 us; speedup 1.0000x reference)
//
#include <hip/hip_runtime.h>
#include <hip/hip_bf16.h>

// Problem constants (from reference)
#define NN 20000
#define EE 320000
#define FF 75
#define GG 64
#define LL 5
#define EPS 1e-5f

// GEMM paddings
#define KUV 96      // K for uv gemm (h: 75 -> 96; col 75 = 1.0 bias trick)
#define NUV 160     // cols: u at 0..74, v at 80..154
#define KPOST 384   // K for post gemm ([h|agg]: 375 -> 384)
#define KLIN 96

#define GATHER_BLOCKS 1024  // persistent-ish gather grid: 4 blocks/CU

typedef short bf16x8 __attribute__((ext_vector_type(8)));
typedef float f32x4 __attribute__((ext_vector_type(4)));

__device__ inline void gAtomicAdd(float* p, float v) { unsafeAtomicAdd(p, v); }

__device__ inline ushort f2bs(float x) {
    __hip_bfloat16 b = __float2bfloat16(x);
    return *(ushort*)&b;
}

__device__ inline float bs2f(ushort u) {
    unsigned int x = ((unsigned int)u) << 16;
    return __uint_as_float(x);
}

#define S_UV (LL * NUV * KUV)
#define S_POST (LL * 240 * KPOST)
#define S_LIN (LL * 80 * KLIN)
#define S_TOT (S_UV + S_POST + S_LIN)

// ---------------- 1: degree count + weight prep (independent work, merged) ----------------

__global__ void countprep_kernel(const int* __restrict__ col, int* __restrict__ cnt,
                                 const float* __restrict__ pre_w, const float* __restrict__ pre_b,
                                 const float* __restrict__ post_w, const float* __restrict__ lin_w,
                                 ushort* __restrict__ BTuv, ushort* __restrict__ BTpost,
                                 ushort* __restrict__ BTlin) {
    int idx0 = blockIdx.x * 256 + threadIdx.x;
    if (idx0 < EE) {
        atomicAdd(&cnt[col[idx0]], 1);
        return;
    }
    int idx = idx0 - EE;
    if (idx < S_UV) {
        int l = idx / (NUV * KUV);
        int r = idx % (NUV * KUV);
        int c = r / KUV, k = r % KUV;
        float v = 0.f;
        if (k < FF) {
            if (c < FF) v = pre_w[((size_t)l * 150 + k) * FF + c];
            else if (c >= 80 && c < 80 + FF) v = pre_w[((size_t)l * 150 + FF + k) * FF + (c - 80)];
        } else if (k == FF && c < FF) {
            v = pre_b[l * FF + c];  // bias fold: A col75 = 1.0
        }
        BTuv[idx] = f2bs(v);
    } else if (idx < S_UV + S_POST) {
        int j = idx - S_UV;
        int l = j / (240 * KPOST);
        int r = j % (240 * KPOST);
        int c = r / KPOST, k = r % KPOST;
        float v = 0.f;
        if (k < FF) {
            if (c < FF) v = post_w[((size_t)l * 975 + k) * FF + c];
        } else if (k < 375) {
            if (c < FF) v = post_w[((size_t)l * 975 + k) * FF + c];
            else if (c >= 80 && c < 80 + FF) v = post_w[((size_t)l * 975 + k + 300) * FF + (c - 80)];
            else if (c >= 160 && c < 160 + FF) v = post_w[((size_t)l * 975 + k + 600) * FF + (c - 160)];
        }
        BTpost[j] = f2bs(v);
    } else if (idx < S_TOT) {
        int j = idx - S_UV - S_POST;
        int l = j / (80 * KLIN);
        int r = j % (80 * KLIN);
        int c = r / KLIN, k = r % KLIN;
        float v = (c < FF && k < FF) ? lin_w[((size_t)l * FF + k) * FF + c] : 0.f;
        BTlin[j] = f2bs(v);
    }
}

// ---------------- 2: dinv + sumlog + CSR segment alloc (atomic base) ----------------

__global__ void dinv_offs_kernel(const int* __restrict__ cnt, float* __restrict__ dinv,
                                 float* __restrict__ scal, int* __restrict__ gcur,
                                 int* __restrict__ offs, int* __restrict__ cursor, int N) {
    __shared__ int sh[256];
    __shared__ float red[256];
    __shared__ int bb;
    int tid = threadIdx.x;
    int i = blockIdx.x * 256 + tid;
    int cv = (i < N) ? cnt[i] : 0;
    float lg = 0.f;
    if (i < N) {
        dinv[i] = rsqrtf((float)cv + 1.f);
        lg = logf((float)cv + 1.f);
    }
    sh[tid] = cv;
    red[tid] = lg;
    __syncthreads();
    for (int d = 1; d < 256; d <<= 1) {
        int t = (tid >= d) ? sh[tid - d] : 0;
        __syncthreads();
        sh[tid] += t;
        __syncthreads();
    }
    if (tid == 255) bb = atomicAdd(gcur, sh[255]);
    __syncthreads();
    int excl = sh[tid] - cv + bb;
    if (i < N) {
        offs[i] = excl;
        cursor[i] = excl;
    }
    for (int s = 128; s > 0; s >>= 1) {
        if (tid < s) red[tid] += red[tid + s];
        __syncthreads();
    }
    if (tid == 0) gAtomicAdd(&scal[0], red[0]);
}

// ---------------- 3: CSR fill + xs prescale ----------------

__global__ void fill_xs_kernel(const int* __restrict__ row, const int* __restrict__ col,
                               int* __restrict__ cursor, int* __restrict__ csr,
                               const float* __restrict__ x, const float* __restrict__ gw,
                               const float* __restrict__ dinv, ushort* __restrict__ xs) {
    int idx = blockIdx.x * 256 + threadIdx.x;
    if (idx < EE) {
        int c = col[idx];
        int pos = atomicAdd(&cursor[c], 1);
        csr[pos] = row[idx];
    } else if (idx < EE + NN * 80) {
        int j = idx - EE;
        int n = j / 80, t = j % 80;
        float v = 0.f;
        if (t < FF) {
            float acc = 0.f;
#pragma unroll
            for (int k = 0; k < 6; k++) acc += x[n * 6 + k] * gw[k * FF + t];
            v = dinv[n] * acc;
        }
        xs[j] = f2bs(v);
    }
}

// ---------------- 4: GCN gather — grid-stride, 1 node/wave/iter, shuffle merge, no LDS ----------------

__global__ __launch_bounds__(256) void gcn_kernel(
    const ushort* __restrict__ xs, const float* __restrict__ dinv,
    const int* __restrict__ offs, const int* __restrict__ csr,
    const float* __restrict__ gcn_b, const int* __restrict__ cnt,
    const float* __restrict__ scal, float* __restrict__ o2,
    float* __restrict__ amp, float* __restrict__ att) {
    int wid = threadIdx.x >> 6, lane = threadIdx.x & 63;
    int nw = gridDim.x * 4;
    int s = lane / 10, f = lane - s * 10;

    int i = blockIdx.x * 4 + wid;
    int s0 = (i < NN) ? offs[i] : 0;
    int deg = (i < NN) ? cnt[i] : 0;
    while (i < NN) {
        // prefetch next node's descriptors (latency hides under edge loop)
        int i2 = i + nw;
        int s0n = (i2 < NN) ? offs[i2] : 0;
        int degn = (i2 < NN) ? cnt[i2] : 0;

        float a[8];
#pragma unroll
        for (int j = 0; j < 8; j++) a[j] = 0.f;
        if (lane < 60) {
            int full = deg / 6;
            int rem = deg - full * 6;
            int iters = full + (s < rem ? 1 : 0);
            int k = s0 + s;
            int r_cur = (iters > 0) ? csr[k] : 0;
            int r_nxt = (iters > 1) ? csr[k + 6] : 0;
            bf16x8 v_cur = *(const bf16x8*)(xs + (size_t)r_cur * 80 + f * 8);
            for (int it = 0; it < iters; it++) {
                int r_fut = (it + 2 < iters) ? csr[k + 12] : 0;
                bf16x8 v_nxt = *(const bf16x8*)(xs + (size_t)r_nxt * 80 + f * 8);
#pragma unroll
                for (int j = 0; j < 8; j++) a[j] += bs2f((ushort)v_cur[j]);
                v_cur = v_nxt;
                r_nxt = r_fut;
                k += 6;
            }
        }
        // merge slots 3..5 into 0..2, then 1,2 into 0
#pragma unroll
        for (int j = 0; j < 8; j++) a[j] += __shfl(a[j], lane + 30);
#pragma unroll
        for (int j = 0; j < 8; j++) a[j] += __shfl(a[j], lane + 10) + __shfl(a[j], lane + 20);

        if (lane < 10) {
            bf16x8 vs = *(const bf16x8*)(xs + (size_t)i * 80 + lane * 8);
            float di = dinv[i];
            float o[8];
#pragma unroll
            for (int j = 0; j < 8; j++) {
                int c = lane * 8 + j;
                float bias = (c < FF) ? gcn_b[c] : 0.f;
                o[j] = di * (a[j] + bs2f((ushort)vs[j])) + bias;
            }
            float* orow = o2 + (size_t)i * 80 + lane * 8;
            *(f32x4*)orow = (f32x4){o[0], o[1], o[2], o[3]};
            *(f32x4*)(orow + 4) = (f32x4){o[4], o[5], o[6], o[7]};
        } else if (lane == 60) {
            float al = scal[0] / (float)NN;
            float d = fmaxf((float)deg, 1.f);
            float lg = logf(d + 1.f);
            amp[i] = lg / al;
            att[i] = al / lg;
        }
        i = i2;
        s0 = s0n;
        deg = degn;
    }
}

// ---------------- uv GEMM (+ fused BN for l>0): 1 wave = 32 rows ----------------

__global__ __launch_bounds__(64) void uv_bn_kernel(
    const float* __restrict__ o2, const float* __restrict__ slots,
    const float* __restrict__ bg, const float* __restrict__ bb, int apply_bn,
    const ushort* __restrict__ BT, float* __restrict__ U, ushort* __restrict__ Vb,
    ushort* __restrict__ hagg) {
    __shared__ float ssL[160];
    int lane = threadIdx.x;
    int col16 = lane & 15, quad = lane >> 4;
    int nA = blockIdx.x * 32 + col16;
    const float* orowA = o2 + (size_t)nA * 80;
    const float* orowB = orowA + 16 * 80;
    const ushort* bbase = BT + (size_t)col16 * KUV + quad * 8;

    if (apply_bn) {
        for (int c = lane; c < 80; c += 64) {
            if (c < FF) {
                float su = 0.f, sq = 0.f;
#pragma unroll 8
                for (int s = 0; s < 32; s++) {
                    su += slots[s * 160 + c];
                    sq += slots[s * 160 + 80 + c];
                }
                float mu = su * (1.f / (float)NN);
                float var = sq * (1.f / (float)NN) - mu * mu;
                float sc = bg[c] * rsqrtf(var + EPS);
                ssL[c] = sc;
                ssL[80 + c] = bb[c] - mu * sc;
            } else {
                ssL[c] = 0.f;
                ssL[80 + c] = 0.f;
            }
        }
        __syncthreads();
    }

    f32x4 accA[10], accB[10];
#pragma unroll
    for (int i = 0; i < 10; i++) {
        accA[i] = (f32x4){0.f, 0.f, 0.f, 0.f};
        accB[i] = (f32x4){0.f, 0.f, 0.f, 0.f};
    }

#pragma unroll
    for (int kt = 0; kt < 3; kt++) {
        int kb = kt * 32 + quad * 8;
        bf16x8 afA, afB;
        if (kb < 80) {
            float4 a0 = *(const float4*)(orowA + kb);
            float4 a1 = *(const float4*)(orowA + kb + 4);
            float4 b0 = *(const float4*)(orowB + kb);
            float4 b1 = *(const float4*)(orowB + kb + 4);
            float vA[8] = {a0.x, a0.y, a0.z, a0.w, a1.x, a1.y, a1.z, a1.w};
            float vB[8] = {b0.x, b0.y, b0.z, b0.w, b1.x, b1.y, b1.z, b1.w};
#pragma unroll
            for (int j = 0; j < 8; j++) {
                int k = kb + j;
                float xA = vA[j], xB = vB[j];
                if (apply_bn) {
                    xA = fmaxf(xA * ssL[k] + ssL[80 + k], 0.f);
                    xB = fmaxf(xB * ssL[k] + ssL[80 + k], 0.f);
                }
                ushort hA = (k < FF) ? f2bs(xA) : (k == FF ? (ushort)0x3F80 : (ushort)0);
                ushort hB = (k < FF) ? f2bs(xB) : (k == FF ? (ushort)0x3F80 : (ushort)0);
                afA[j] = (short)hA;
                afB[j] = (short)hB;
            }
            if (kb < FF) {
                // h-cols of hagg; forced values at cols 75..79 overwritten by edge_agg
                *(bf16x8*)(hagg + (size_t)nA * KPOST + kb) = afA;
                *(bf16x8*)(hagg + (size_t)(nA + 16) * KPOST + kb) = afB;
            }
        } else {
            afA = (bf16x8){0, 0, 0, 0, 0, 0, 0, 0};
            afB = (bf16x8){0, 0, 0, 0, 0, 0, 0, 0};
        }
#pragma unroll
        for (int nt = 0; nt < 10; nt++) {
            bf16x8 bfr = *(const bf16x8*)(bbase + nt * (16 * KUV) + kt * 32);
            accA[nt] = __builtin_amdgcn_mfma_f32_16x16x32_bf16(afA, bfr, accA[nt], 0, 0, 0);
            accB[nt] = __builtin_amdgcn_mfma_f32_16x16x32_bf16(afB, bfr, accB[nt], 0, 0, 0);
        }
    }
    int n0 = blockIdx.x * 32;
#pragma unroll
    for (int nt = 0; nt < 10; nt++) {
        int col = nt * 16 + col16;
#pragma unroll
        for (int r = 0; r < 4; r++) {
            int nnA = n0 + quad * 4 + r;
            int nnB = nnA + 16;
            if (col < FF) {
                U[(size_t)nnA * 80 + col] = accA[nt][r];
                U[(size_t)nnB * 80 + col] = accB[nt][r];
            } else if (col >= 80 && col < 80 + FF) {
                Vb[(size_t)nnA * 80 + (col - 80)] = f2bs(accA[nt][r]);
                Vb[(size_t)nnB * 80 + (col - 80)] = f2bs(accB[nt][r]);
            }
        }
    }
}

// ---------------- edge aggregation — grid-stride, 1 node/wave/iter, shuffle merge, no LDS ----------------

__global__ __launch_bounds__(256) void edge_agg_kernel(
    const float* __restrict__ U, const ushort* __restrict__ V,
    const int* __restrict__ offs, const int* __restrict__ csr,
    const int* __restrict__ cnt, ushort* __restrict__ hagg) {
    int wid = threadIdx.x >> 6, lane = threadIdx.x & 63;
    int nw = gridDim.x * 4;
    int s = lane / 10, f = lane - s * 10;

    int i = blockIdx.x * 4 + wid;
    int s0 = (i < NN) ? offs[i] : 0;
    int deg = (i < NN) ? cnt[i] : 0;
    while (i < NN) {
        int i2 = i + nw;
        int s0n = (i2 < NN) ? offs[i2] : 0;
        int degn = (i2 < NN) ? cnt[i2] : 0;

        float sa[8], sq[8], mn[8], mx[8];
#pragma unroll
        for (int j = 0; j < 8; j++) {
            sa[j] = 0.f; sq[j] = 0.f; mn[j] = 1e30f; mx[j] = -1e30f;
        }
        if (lane < 60) {
            int full = deg / 6;
            int rem = deg - full * 6;
            int iters = full + (s < rem ? 1 : 0);
            int k = s0 + s;
            int r_cur = (iters > 0) ? csr[k] : 0;
            int r_nxt = (iters > 1) ? csr[k + 6] : 0;
            bf16x8 v_cur = *(const bf16x8*)(V + (size_t)r_cur * 80 + f * 8);
            for (int it = 0; it < iters; it++) {
                int r_fut = (it + 2 < iters) ? csr[k + 12] : 0;
                bf16x8 v_nxt = *(const bf16x8*)(V + (size_t)r_nxt * 80 + f * 8);
#pragma unroll
                for (int j = 0; j < 8; j++) {
                    float xv = bs2f((ushort)v_cur[j]);
                    sa[j] += xv;
                    sq[j] += xv * xv;
                    mn[j] = fminf(mn[j], xv);
                    mx[j] = fmaxf(mx[j], xv);
                }
                v_cur = v_nxt;
                r_nxt = r_fut;
                k += 6;
            }
        }
        // merge: slots 3..5 -> 0..2, then 1,2 -> 0
#pragma unroll
        for (int j = 0; j < 8; j++) {
            sa[j] += __shfl(sa[j], lane + 30);
            sq[j] += __shfl(sq[j], lane + 30);
            mn[j] = fminf(mn[j], __shfl(mn[j], lane + 30));
            mx[j] = fmaxf(mx[j], __shfl(mx[j], lane + 30));
        }
#pragma unroll
        for (int j = 0; j < 8; j++) {
            sa[j] += __shfl(sa[j], lane + 10) + __shfl(sa[j], lane + 20);
            sq[j] += __shfl(sq[j], lane + 10) + __shfl(sq[j], lane + 20);
            mn[j] = fminf(mn[j], fminf(__shfl(mn[j], lane + 10), __shfl(mn[j], lane + 20)));
            mx[j] = fmaxf(mx[j], fmaxf(__shfl(mx[j], lane + 10), __shfl(mx[j], lane + 20)));
        }

        if (lane < 10) {
            float cf = (float)deg;
            float inv = 1.f / fmaxf(cf, 1.f);
            const float* up = U + (size_t)i * 80 + lane * 8;
            float4 u0 = *(const float4*)up;
            float4 u1 = *(const float4*)(up + 4);
            float u[8] = {u0.x, u0.y, u0.z, u0.w, u1.x, u1.y, u1.z, u1.w};
            ushort* a = hagg + (size_t)i * KPOST + FF;
#pragma unroll
            for (int j = 0; j < 8; j++) {
                int c = lane * 8 + j;
                if (c < FF) {
                    float m = (u[j] * cf + sa[j]) * inv;
                    float ev = sa[j] * inv;
                    float st = sqrtf(fmaxf(sq[j] * inv - ev * ev, 0.f) + EPS);
                    float mno = (deg > 0) ? (u[j] + mn[j]) : 0.f;
                    float mxo = (deg > 0) ? (u[j] + mx[j]) : 0.f;
                    a[c] = f2bs(m);
                    a[FF + c] = f2bs(mno);
                    a[2 * FF + c] = f2bs(mxo);
                    a[3 * FF + c] = f2bs(st);
                }
            }
        } else if (lane >= 48 && lane < 57) {
            hagg[(size_t)i * KPOST + 375 + (lane - 48)] = 0;  // K-pad
        }
        i = i2;
        s0 = s0n;
        deg = degn;
    }
}

// ---------------- post GEMM + combine + lin GEMM + BN stats (1 wave = 32 rows) ----------------

__global__ __launch_bounds__(64) void post_lin_kernel(
    const ushort* __restrict__ A, const ushort* __restrict__ BT,
    const ushort* __restrict__ BL, const float* __restrict__ amp,
    const float* __restrict__ att, float* __restrict__ o2,
    float* __restrict__ slots) {
    __shared__ __align__(16) ushort olds[32 * 104];
    int lane = threadIdx.x;
    int col16 = lane & 15, quad = lane >> 4, kseg = quad * 8;
    int n0 = blockIdx.x * 32;
    const ushort* arowA = A + (size_t)(n0 + col16) * KPOST + kseg;
    const ushort* arowB = arowA + (size_t)16 * KPOST;
    const ushort* bbase = BT + (size_t)col16 * KPOST + kseg;

    f32x4 accA[15], accB[15];
#pragma unroll
    for (int i = 0; i < 15; i++) {
        accA[i] = (f32x4){0.f, 0.f, 0.f, 0.f};
        accB[i] = (f32x4){0.f, 0.f, 0.f, 0.f};
    }

#pragma unroll 2
    for (int kt = 0; kt < 12; kt++) {
        bf16x8 afA = *(const bf16x8*)(arowA + kt * 32);
        bf16x8 afB = *(const bf16x8*)(arowB + kt * 32);
#pragma unroll
        for (int nt = 0; nt < 15; nt++) {
            bf16x8 bfr = *(const bf16x8*)(bbase + (size_t)nt * (16 * KPOST) + kt * 32);
            accA[nt] = __builtin_amdgcn_mfma_f32_16x16x32_bf16(afA, bfr, accA[nt], 0, 0, 0);
            accB[nt] = __builtin_amdgcn_mfma_f32_16x16x32_bf16(afB, bfr, accB[nt], 0, 0, 0);
        }
    }
    float ampA[4], attA[4], ampB[4], attB[4];
#pragma unroll
    for (int r = 0; r < 4; r++) {
        int n = n0 + quad * 4 + r;
        ampA[r] = amp[n];
        attA[r] = att[n];
        ampB[r] = amp[n + 16];
        attB[r] = att[n + 16];
    }
#pragma unroll
    for (int g = 0; g < 5; g++) {
        int col = g * 16 + col16;
#pragma unroll
        for (int r = 0; r < 4; r++) {
            float ovA = accA[g][r] + ampA[r] * accA[g + 5][r] + attA[r] * accA[g + 10][r];
            float ovB = accB[g][r] + ampB[r] * accB[g + 5][r] + attB[r] * accB[g + 10][r];
            olds[(quad * 4 + r) * 104 + col] = (col < FF) ? f2bs(ovA) : (ushort)0;
            olds[(16 + quad * 4 + r) * 104 + col] = (col < FF) ? f2bs(ovB) : (ushort)0;
        }
    }
    {
        int rr = lane >> 1, cc = 80 + (lane & 1) * 8;
        *(bf16x8*)(olds + rr * 104 + cc) = (bf16x8){0, 0, 0, 0, 0, 0, 0, 0};
    }
    __syncthreads();

    f32x4 acc2A[5], acc2B[5];
#pragma unroll
    for (int i = 0; i < 5; i++) {
        acc2A[i] = (f32x4){0.f, 0.f, 0.f, 0.f};
        acc2B[i] = (f32x4){0.f, 0.f, 0.f, 0.f};
    }
    const ushort* blbase = BL + (size_t)col16 * KLIN + kseg;
#pragma unroll
    for (int kt = 0; kt < 3; kt++) {
        bf16x8 afA = *(const bf16x8*)(olds + col16 * 104 + kt * 32 + kseg);
        bf16x8 afB = *(const bf16x8*)(olds + (16 + col16) * 104 + kt * 32 + kseg);
#pragma unroll
        for (int nt = 0; nt < 5; nt++) {
            bf16x8 bfr = *(const bf16x8*)(blbase + nt * (16 * KLIN) + kt * 32);
            acc2A[nt] = __builtin_amdgcn_mfma_f32_16x16x32_bf16(afA, bfr, acc2A[nt], 0, 0, 0);
            acc2B[nt] = __builtin_amdgcn_mfma_f32_16x16x32_bf16(afB, bfr, acc2B[nt], 0, 0, 0);
        }
    }
    float* slot = slots + (blockIdx.x & 31) * 160;
#pragma unroll
    for (int nt = 0; nt < 5; nt++) {
        int col = nt * 16 + col16;
        float s = 0.f, q = 0.f;
#pragma unroll
        for (int r = 0; r < 4; r++) {
            int nA = n0 + quad * 4 + r;
            float vA = acc2A[nt][r];
            float vB = acc2B[nt][r];
            if (col < FF) {
                o2[(size_t)nA * 80 + col] = vA;
                o2[(size_t)(nA + 16) * 80 + col] = vB;
                s += vA + vB;
                q += vA * vA + vB * vB;
            }
        }
        s += __shfl_xor(s, 16); s += __shfl_xor(s, 32);
        q += __shfl_xor(q, 16); q += __shfl_xor(q, 32);
        if (lane < 16 && col < FF) {
            gAtomicAdd(&slot[col], s);
            gAtomicAdd(&slot[80 + col], q);
        }
    }
}

// ---------------- pool (BN inline) + final MLP fused: one block per graph ----------------

__global__ __launch_bounds__(256) void pool_mlp_kernel(
    const float* __restrict__ o2, const float* __restrict__ slots,
    const float* __restrict__ bg, const float* __restrict__ bb,
    const int* __restrict__ batch,
    const float* __restrict__ w1, const float* __restrict__ b1,
    const float* __restrict__ w2, const float* __restrict__ b2,
    const float* __restrict__ w3, const float* __restrict__ b3,
    float* __restrict__ out) {
    __shared__ float ssL[160];
    __shared__ float part[3][80];
    __shared__ float gr[80], h1[50], h2[25];
    int gi = blockIdx.x, tid = threadIdx.x;
    for (int c = tid; c < 80; c += 256) {
        if (c < FF) {
            float su = 0.f, sq = 0.f;
#pragma unroll 8
            for (int s = 0; s < 32; s++) {
                su += slots[s * 160 + c];
                sq += slots[s * 160 + 80 + c];
            }
            float mu = su * (1.f / (float)NN);
            float var = sq * (1.f / (float)NN) - mu * mu;
            float sc = bg[c] * rsqrtf(var + EPS);
            ssL[c] = sc;
            ssL[80 + c] = bb[c] - mu * sc;
        } else {
            ssL[c] = 0.f;
            ssL[80 + c] = 0.f;
        }
    }
    __syncthreads();
    int lo, hi;
    {
        int a = 0, b = NN;
        while (a < b) { int m = (a + b) >> 1; if (batch[m] < gi) a = m + 1; else b = m; }
        lo = a;
        b = NN;
        while (a < b) { int m = (a + b) >> 1; if (batch[m] < gi + 1) a = m + 1; else b = m; }
        hi = a;
    }
    if (tid < 240) {
        int c = tid % 80, sub = tid / 80;
        float acc = 0.f;
        if (c < FF) {
            for (int n = lo + sub; n < hi; n += 3)
                acc += fmaxf(o2[(size_t)n * 80 + c] * ssL[c] + ssL[80 + c], 0.f);
        }
        part[sub][c] = acc;
    }
    __syncthreads();
    if (tid < 80) gr[tid] = part[0][tid] + part[1][tid] + part[2][tid];
    __syncthreads();
    if (tid < 50) {
        float a = b1[tid];
        for (int k = 0; k < FF; k++) a += gr[k] * w1[k * 50 + tid];
        h1[tid] = fmaxf(a, 0.f);
    }
    __syncthreads();
    if (tid < 25) {
        float a = b2[tid];
        for (int k = 0; k < 50; k++) a += h1[k] * w2[k * 25 + tid];
        h2[tid] = fmaxf(a, 0.f);
    }
    __syncthreads();
    if (tid < 10) {
        float a = b3[tid];
        for (int k = 0; k < 25; k++) a += h2[k] * w3[k * 10 + tid];
        out[gi * 10 + tid] = a;
    }
}

// ---------------- launch ----------------

extern "C" void kernel_launch(void* const* d_in, const int* in_sizes, int n_in,
                              void* d_out, int out_size, void* d_ws, size_t ws_size,
                              hipStream_t stream) {
    const float* x = (const float*)d_in[0];
    const int* ei = (const int*)d_in[1];
    const int* batch = (const int*)d_in[2];
    const float* gcn_w = (const float*)d_in[3];
    const float* gcn_b = (const float*)d_in[4];
    const float* pre_w = (const float*)d_in[5];
    const float* pre_b = (const float*)d_in[6];
    const float* post_w = (const float*)d_in[7];
    const float* lin_w = (const float*)d_in[9];
    const float* bn_g = (const float*)d_in[11];
    const float* bn_b = (const float*)d_in[12];
    const float* w1 = (const float*)d_in[13];
    const float* b1 = (const float*)d_in[14];
    const float* w2 = (const float*)d_in[15];
    const float* b2 = (const float*)d_in[16];
    const float* w3 = (const float*)d_in[17];
    const float* b3 = (const float*)d_in[18];
    float* out = (float*)d_out;

    const int* row = ei;
    const int* col = ei + EE;

    char* ws = (char*)d_ws;
    size_t off = 0;
    auto alloc = [&](size_t bytes) {
        char* p = ws + off;
        off += (bytes + 255) & ~(size_t)255;
        return p;
    };
    // zero-region: cnt + scal(+slots) + gcur adjacent, single memset
    size_t z0 = off;
    int* cnt = (int*)alloc(NN * 4);
    float* scal = (float*)alloc((1 + LL * 32 * 160) * 4);  // [0]=sumlog; slots[5][32][160]
    int* gcur = (int*)alloc(256);
    size_t z1 = off;
    float* slotbase = scal + 1;
    int* offs = (int*)alloc(NN * 4);
    int* cursor = (int*)alloc(NN * 4);
    int* csr = (int*)alloc(EE * 4);
    float* dinv = (float*)alloc(NN * 4);
    float* amp = (float*)alloc(NN * 4);
    float* att = (float*)alloc(NN * 4);
    float* o2 = (float*)alloc((size_t)NN * 80 * 4);
    float* ubuf = (float*)alloc((size_t)NN * 80 * 4);
    ushort* xsbuf = (ushort*)alloc((size_t)NN * 80 * 2);
    ushort* vbuf = (ushort*)alloc((size_t)NN * 80 * 2);
    ushort* hagg = (ushort*)alloc((size_t)NN * KPOST * 2);
    ushort* BTuv = (ushort*)alloc((size_t)S_UV * 2);
    ushort* BTpost = (ushort*)alloc((size_t)S_POST * 2);
    ushort* BTlin = (ushort*)alloc((size_t)S_LIN * 2);

    hipMemsetAsync(ws + z0, 0, z1 - z0, stream);

    const int B = 256;
    const int NB = (NN + 255) / 256;  // 79
    countprep_kernel<<<(EE + S_TOT + B - 1) / B, B, 0, stream>>>(col, cnt, pre_w, pre_b,
                                                                 post_w, lin_w,
                                                                 BTuv, BTpost, BTlin);
    dinv_offs_kernel<<<NB, B, 0, stream>>>(cnt, dinv, scal, gcur, offs, cursor, NN);
    fill_xs_kernel<<<(EE + NN * 80 + B - 1) / B, B, 0, stream>>>(row, col, cursor, csr,
                                                                 x, gcn_w, dinv, xsbuf);
    gcn_kernel<<<GATHER_BLOCKS, B, 0, stream>>>(xsbuf, dinv, offs, csr, gcn_b, cnt, scal,
                                                o2, amp, att);

    const int GS2 = NN / 32;  // 625 single-wave blocks, 32 rows each
    for (int l = 0; l < LL; l++) {
        float* slots = slotbase + (size_t)l * 32 * 160;
        int lp = (l > 0) ? (l - 1) : 0;
        int ab = (l > 0) ? 1 : 0;
        const float* sp = (l == 0) ? slotbase : slotbase + (size_t)(l - 1) * 32 * 160;

        uv_bn_kernel<<<GS2, 64, 0, stream>>>(o2, sp, bn_g + lp * FF, bn_b + lp * FF, ab,
                                             BTuv + (size_t)l * NUV * KUV, ubuf, vbuf, hagg);
        edge_agg_kernel<<<GATHER_BLOCKS, B, 0, stream>>>(ubuf, vbuf, offs, csr, cnt, hagg);
        post_lin_kernel<<<GS2, 64, 0, stream>>>(hagg, BTpost + (size_t)l * 240 * KPOST,
                                                BTlin + (size_t)l * 80 * KLIN, amp, att,
                                                o2, slots);
    }

    pool_mlp_kernel<<<GG, B, 0, stream>>>(o2, slotbase + (size_t)(LL - 1) * 32 * 160,
                                          bn_g + (LL - 1) * FF, bn_b + (LL - 1) * FF,
                                          batch, w1, b1, w2, b2, w3, b3, out);
}